// Round 1
// baseline (2491.498 us; speedup 1.0000x reference)
//
#include <hip/hip_runtime.h>
#include <math.h>

#define B_ 128
#define L_ 8192
#define C_ 32
#define F_ 10
#define NSIG (B_*C_)     // 4096 independent signals
#define LOG2L 13

// Twiddle table W_L^k = exp(-2*pi*i*k/L), k in [0, L/2)
__device__ float2 g_tw[L_/2];

__global__ void make_twiddles_kernel() {
    int k = blockIdx.x * blockDim.x + threadIdx.x;
    if (k < L_/2) {
        double a = -2.0 * 3.14159265358979323846 * (double)k / (double)L_;
        g_tw[k] = make_float2((float)cos(a), (float)sin(a));
    }
}

// x (B, L, C) -> xT (B*C, L)   [coalesced both sides via LDS tile]
__global__ __launch_bounds__(256) void transpose_kernel(const float* __restrict__ x,
                                                        float* __restrict__ xT) {
    __shared__ float t[32][33];
    int b  = blockIdx.y;
    int l0 = blockIdx.x * 32;
    int tx = threadIdx.x;   // 0..31
    int ty = threadIdx.y;   // 0..7
    #pragma unroll
    for (int r = 0; r < 4; ++r) {
        int l = l0 + ty + r*8;
        t[ty + r*8][tx] = x[(size_t)b * (L_*C_) + (size_t)l * C_ + tx];
    }
    __syncthreads();
    #pragma unroll
    for (int r = 0; r < 4; ++r) {
        int c = ty + r*8;
        xT[((size_t)(b*C_ + c)) * L_ + (l0 + tx)] = t[tx][c];
    }
}

// One block per signal: forward FFT -> threshold -> inverse FFT -> ref = x - denoised
// In-place over xT (reads original row again before overwriting).
__global__ __launch_bounds__(256) void fft_denoise_kernel(float* __restrict__ xT) {
    __shared__ float2 D[L_];      // 64 KB
    __shared__ float red[256];
    const int tid = threadIdx.x;
    const size_t base = (size_t)blockIdx.x * L_;

    // load input into bit-reversed positions (real -> complex)
    for (int i = tid; i < L_; i += 256) {
        float v = xT[base + i];
        int j = (int)(__brev((unsigned)i) >> (32 - LOG2L));
        D[j] = make_float2(v, 0.0f);
    }
    __syncthreads();

    // forward FFT: 13 radix-2 DIT stages
    for (int s = 1; s <= LOG2L; ++s) {
        const int half  = 1 << (s - 1);
        const int shift = LOG2L - s;
        for (int t = tid; t < (L_/2); t += 256) {
            int o  = t & (half - 1);
            int g  = t >> (s - 1);
            int i0 = (g << s) + o;
            int i1 = i0 + half;
            float2 w = g_tw[o << shift];
            float2 a = D[i0], b = D[i1];
            float2 wb = make_float2(w.x*b.x - w.y*b.y, w.x*b.y + w.y*b.x);
            D[i0] = make_float2(a.x + wb.x, a.y + wb.y);
            D[i1] = make_float2(a.x - wb.x, a.y - wb.y);
        }
        __syncthreads();
    }

    // max |F|^2 over the signal
    float m = 0.0f;
    for (int i = tid; i < L_; i += 256) {
        float2 v = D[i];
        m = fmaxf(m, v.x*v.x + v.y*v.y);
    }
    red[tid] = m;
    __syncthreads();
    for (int w = 128; w > 0; w >>= 1) {
        if (tid < w) red[tid] = fmaxf(red[tid], red[tid + w]);
        __syncthreads();
    }
    const float thr2 = 0.01f * red[0];   // (0.1*max_mag)^2 compared against mag^2

    // zero bins with mag < thr  (mag^2 < thr^2)
    for (int i = tid; i < L_; i += 256) {
        float2 v = D[i];
        float m2 = v.x*v.x + v.y*v.y;
        if (m2 < thr2) D[i] = make_float2(0.0f, 0.0f);
    }
    __syncthreads();

    // bit-reverse permute (natural -> bit-reversed) for inverse DIT
    for (int i = tid; i < L_; i += 256) {
        int j = (int)(__brev((unsigned)i) >> (32 - LOG2L));
        if (i < j) { float2 a = D[i]; D[i] = D[j]; D[j] = a; }
    }
    __syncthreads();

    // inverse FFT: conjugate twiddles
    for (int s = 1; s <= LOG2L; ++s) {
        const int half  = 1 << (s - 1);
        const int shift = LOG2L - s;
        for (int t = tid; t < (L_/2); t += 256) {
            int o  = t & (half - 1);
            int g  = t >> (s - 1);
            int i0 = (g << s) + o;
            int i1 = i0 + half;
            float2 w = g_tw[o << shift];   // conj applied below
            float2 a = D[i0], b = D[i1];
            float2 wb = make_float2(w.x*b.x + w.y*b.y, w.x*b.y - w.y*b.x);
            D[i0] = make_float2(a.x + wb.x, a.y + wb.y);
            D[i1] = make_float2(a.x - wb.x, a.y - wb.y);
        }
        __syncthreads();
    }

    // ref = x - ifft.real / N   (in place)
    const float invN = 1.0f / (float)L_;
    for (int i = tid; i < L_; i += 256) {
        float xv  = xT[base + i];
        float den = D[i].x * invN;
        xT[base + i] = xv - den;
    }
}

// Sequential LMS: one thread per (b,c) chain.
__global__ __launch_bounds__(64) void lms_kernel(const float* __restrict__ x,
                                                 const float* __restrict__ refT,
                                                 const float* __restrict__ w0,
                                                 float* __restrict__ out) {
    const int t = blockIdx.x * 64 + threadIdx.x;   // 0..4095
    const int b = t >> 5;
    const int c = t & 31;
    const float* xrow   = x   + (size_t)b * (L_*C_) + c;
    float*       outrow = out + (size_t)b * (L_*C_) + c;
    const float* ref    = refT + (size_t)t * L_;

    float w[F_];
    #pragma unroll
    for (int k = 0; k < F_; ++k) w[k] = w0[(size_t)b * (F_*C_) + k*C_ + c];

    // window regs: r[k] = ref[n-1-k]; init for n = F
    float r[F_];
    #pragma unroll
    for (int k = 0; k < F_; ++k) r[k] = ref[F_ - 1 - k];

    // first F outputs: passthrough of x
    #pragma unroll
    for (int n = 0; n < F_; ++n) outrow[(size_t)n * C_] = xrow[(size_t)n * C_];

    for (int n = F_; n < L_; ++n) {
        float y = 0.0f;
        #pragma unroll
        for (int k = 0; k < F_; ++k) y = fmaf(w[k], r[k], y);
        float d = xrow[(size_t)n * C_];
        float e = d - y;
        outrow[(size_t)n * C_] = e;
        float coef = 0.02f * e;          // 2 * MU
        #pragma unroll
        for (int k = 0; k < F_; ++k) w[k] = fmaf(coef, r[k], w[k]);
        #pragma unroll
        for (int k = F_ - 1; k > 0; --k) r[k] = r[k-1];
        r[0] = ref[n];
    }
}

extern "C" void kernel_launch(void* const* d_in, const int* in_sizes, int n_in,
                              void* d_out, int out_size, void* d_ws, size_t ws_size,
                              hipStream_t stream) {
    const float* x  = (const float*)d_in[0];   // (128, 8192, 32)
    const float* w0 = (const float*)d_in[1];   // (128, 10, 32)
    float* out = (float*)d_out;                // (128, 8192, 32)
    float* xT  = (float*)d_ws;                 // (4096, 8192) -> becomes refT in place

    make_twiddles_kernel<<<dim3((L_/2 + 255)/256), dim3(256), 0, stream>>>();
    transpose_kernel<<<dim3(L_/32, B_), dim3(32, 8), 0, stream>>>(x, xT);
    fft_denoise_kernel<<<dim3(NSIG), dim3(256), 0, stream>>>(xT);
    lms_kernel<<<dim3(NSIG/64), dim3(64), 0, stream>>>(x, xT, w0, out);
}

// Round 2
// 1383.433 us; speedup vs baseline: 1.8010x; 1.8010x over previous
//
#include <hip/hip_runtime.h>
#include <math.h>

#define B_ 128
#define L_ 8192
#define C_ 32
#define F_ 10
#define NSIG (B_*C_)     // 4096 independent signals
#define LOG2L 13
#define KCH 16           // LMS prefetch chunk

// Twiddle table W_L^k = exp(-2*pi*i*k/L), k in [0, L/2)
__device__ float2 g_tw[L_/2];

__global__ void make_twiddles_kernel() {
    int k = blockIdx.x * blockDim.x + threadIdx.x;
    if (k < L_/2) {
        double a = -2.0 * 3.14159265358979323846 * (double)k / (double)L_;
        g_tw[k] = make_float2((float)cos(a), (float)sin(a));
    }
}

// x (B, L, C) -> xT (B*C, L)   [coalesced both sides via LDS tile]
__global__ __launch_bounds__(256) void transpose_kernel(const float* __restrict__ x,
                                                        float* __restrict__ xT) {
    __shared__ float t[32][33];
    int b  = blockIdx.y;
    int l0 = blockIdx.x * 32;
    int tx = threadIdx.x;   // 0..31
    int ty = threadIdx.y;   // 0..7
    #pragma unroll
    for (int r = 0; r < 4; ++r) {
        int l = l0 + ty + r*8;
        t[ty + r*8][tx] = x[(size_t)b * (L_*C_) + (size_t)l * C_ + tx];
    }
    __syncthreads();
    #pragma unroll
    for (int r = 0; r < 4; ++r) {
        int c = ty + r*8;
        xT[((size_t)(b*C_ + c)) * L_ + (l0 + tx)] = t[tx][c];
    }
}

// One block per signal: forward FFT -> threshold -> inverse FFT -> ref = x - denoised
__global__ __launch_bounds__(256) void fft_denoise_kernel(float* __restrict__ xT) {
    __shared__ float2 D[L_];      // 64 KB
    __shared__ float red[256];
    const int tid = threadIdx.x;
    const size_t base = (size_t)blockIdx.x * L_;

    for (int i = tid; i < L_; i += 256) {
        float v = xT[base + i];
        int j = (int)(__brev((unsigned)i) >> (32 - LOG2L));
        D[j] = make_float2(v, 0.0f);
    }
    __syncthreads();

    for (int s = 1; s <= LOG2L; ++s) {
        const int half  = 1 << (s - 1);
        const int shift = LOG2L - s;
        for (int t = tid; t < (L_/2); t += 256) {
            int o  = t & (half - 1);
            int g  = t >> (s - 1);
            int i0 = (g << s) + o;
            int i1 = i0 + half;
            float2 w = g_tw[o << shift];
            float2 a = D[i0], b = D[i1];
            float2 wb = make_float2(w.x*b.x - w.y*b.y, w.x*b.y + w.y*b.x);
            D[i0] = make_float2(a.x + wb.x, a.y + wb.y);
            D[i1] = make_float2(a.x - wb.x, a.y - wb.y);
        }
        __syncthreads();
    }

    float m = 0.0f;
    for (int i = tid; i < L_; i += 256) {
        float2 v = D[i];
        m = fmaxf(m, v.x*v.x + v.y*v.y);
    }
    red[tid] = m;
    __syncthreads();
    for (int w = 128; w > 0; w >>= 1) {
        if (tid < w) red[tid] = fmaxf(red[tid], red[tid + w]);
        __syncthreads();
    }
    const float thr2 = 0.01f * red[0];

    for (int i = tid; i < L_; i += 256) {
        float2 v = D[i];
        float m2 = v.x*v.x + v.y*v.y;
        if (m2 < thr2) D[i] = make_float2(0.0f, 0.0f);
    }
    __syncthreads();

    for (int i = tid; i < L_; i += 256) {
        int j = (int)(__brev((unsigned)i) >> (32 - LOG2L));
        if (i < j) { float2 a = D[i]; D[i] = D[j]; D[j] = a; }
    }
    __syncthreads();

    for (int s = 1; s <= LOG2L; ++s) {
        const int half  = 1 << (s - 1);
        const int shift = LOG2L - s;
        for (int t = tid; t < (L_/2); t += 256) {
            int o  = t & (half - 1);
            int g  = t >> (s - 1);
            int i0 = (g << s) + o;
            int i1 = i0 + half;
            float2 w = g_tw[o << shift];
            float2 a = D[i0], b = D[i1];
            float2 wb = make_float2(w.x*b.x + w.y*b.y, w.x*b.y - w.y*b.x);
            D[i0] = make_float2(a.x + wb.x, a.y + wb.y);
            D[i1] = make_float2(a.x - wb.x, a.y - wb.y);
        }
        __syncthreads();
    }

    const float invN = 1.0f / (float)L_;
    for (int i = tid; i < L_; i += 256) {
        float xv  = xT[base + i];
        float den = D[i].x * invN;
        xT[base + i] = xv - den;
    }
}

// Sequential LMS with chunked double-buffered register prefetch.
// One thread per (b,c) chain; loads for chunk c+1 issue before compute of chunk c.

#define LMS_LOADC(cbase, xb, rb) do {                                          \
    _Pragma("unroll")                                                          \
    for (int i_ = 0; i_ < KCH; ++i_)                                           \
        xb[i_] = xrow[(size_t)((cbase) + i_) * C_];                            \
    _Pragma("unroll")                                                          \
    for (int q_ = 0; q_ < KCH/4; ++q_) {                                       \
        float4 v_ = *reinterpret_cast<const float4*>(ref + (cbase) + q_*4);    \
        rb[q_*4+0] = v_.x; rb[q_*4+1] = v_.y;                                  \
        rb[q_*4+2] = v_.z; rb[q_*4+3] = v_.w;                                  \
    }                                                                          \
} while (0)

#define LMS_COMPUTE(cbase, xb, rb) do {                                        \
    _Pragma("unroll")                                                          \
    for (int i_ = 0; i_ < KCH; ++i_) {                                         \
        float y_ = 0.0f;                                                       \
        _Pragma("unroll")                                                      \
        for (int k_ = 0; k_ < F_; ++k_) y_ = fmaf(w[k_], r[k_], y_);           \
        float e_ = xb[i_] - y_;                                                \
        outrow[(size_t)((cbase) + i_) * C_] = e_;                              \
        float coef_ = 0.02f * e_;                                              \
        _Pragma("unroll")                                                      \
        for (int k_ = 0; k_ < F_; ++k_) w[k_] = fmaf(coef_, r[k_], w[k_]);     \
        _Pragma("unroll")                                                      \
        for (int k_ = F_ - 1; k_ > 0; --k_) r[k_] = r[k_-1];                   \
        r[0] = rb[i_];                                                         \
    }                                                                          \
} while (0)

__global__ __launch_bounds__(64) void lms_kernel(const float* __restrict__ x,
                                                 const float* __restrict__ refT,
                                                 const float* __restrict__ w0,
                                                 float* __restrict__ out) {
    const int t = blockIdx.x * 64 + threadIdx.x;   // 0..4095
    const int b = t >> 5;
    const int c = t & 31;
    const float* xrow   = x   + (size_t)b * (L_*C_) + c;
    float*       outrow = out + (size_t)b * (L_*C_) + c;
    const float* ref    = refT + (size_t)t * L_;

    float w[F_];
    #pragma unroll
    for (int k = 0; k < F_; ++k) w[k] = w0[(size_t)b * (F_*C_) + k*C_ + c];

    // ref[0..15] for window init + iterations n=10..15
    float r16[16];
    #pragma unroll
    for (int q = 0; q < 4; ++q) {
        float4 v = *reinterpret_cast<const float4*>(ref + q*4);
        r16[q*4+0] = v.x; r16[q*4+1] = v.y; r16[q*4+2] = v.z; r16[q*4+3] = v.w;
    }

    float r[F_];
    #pragma unroll
    for (int k = 0; k < F_; ++k) r[k] = r16[F_ - 1 - k];

    // first F outputs: passthrough of x
    #pragma unroll
    for (int n = 0; n < F_; ++n) outrow[(size_t)n * C_] = xrow[(size_t)n * C_];

    // n = 10..15 (align main loop to 16)
    #pragma unroll
    for (int n = F_; n < 16; ++n) {
        float y = 0.0f;
        #pragma unroll
        for (int k = 0; k < F_; ++k) y = fmaf(w[k], r[k], y);
        float d = xrow[(size_t)n * C_];
        float e = d - y;
        outrow[(size_t)n * C_] = e;
        float coef = 0.02f * e;
        #pragma unroll
        for (int k = 0; k < F_; ++k) w[k] = fmaf(coef, r[k], w[k]);
        #pragma unroll
        for (int k = F_ - 1; k > 0; --k) r[k] = r[k-1];
        r[0] = r16[n];
    }

    // main loop: n = 16..8191 in 511 chunks of 16, double-buffered prefetch
    float xA[KCH], rA[KCH], xB[KCH], rB[KCH];
    LMS_LOADC(16, xA, rA);
    int cb = 16;
    for (int p = 0; p < 255; ++p) {           // 255 pairs = 510 chunks
        LMS_LOADC(cb + KCH, xB, rB);
        LMS_COMPUTE(cb, xA, rA);
        LMS_LOADC(cb + 2*KCH, xA, rA);
        LMS_COMPUTE(cb + KCH, xB, rB);
        cb += 2*KCH;
    }
    LMS_COMPUTE(cb, xA, rA);                  // cb == 8176, covers n..8191
}

extern "C" void kernel_launch(void* const* d_in, const int* in_sizes, int n_in,
                              void* d_out, int out_size, void* d_ws, size_t ws_size,
                              hipStream_t stream) {
    const float* x  = (const float*)d_in[0];   // (128, 8192, 32)
    const float* w0 = (const float*)d_in[1];   // (128, 10, 32)
    float* out = (float*)d_out;                // (128, 8192, 32)
    float* xT  = (float*)d_ws;                 // (4096, 8192) -> becomes refT in place

    make_twiddles_kernel<<<dim3((L_/2 + 255)/256), dim3(256), 0, stream>>>();
    transpose_kernel<<<dim3(L_/32, B_), dim3(32, 8), 0, stream>>>(x, xT);
    fft_denoise_kernel<<<dim3(NSIG), dim3(256), 0, stream>>>(xT);
    lms_kernel<<<dim3(NSIG/64), dim3(64), 0, stream>>>(x, xT, w0, out);
}